// Round 16
// baseline (130.037 us; speedup 1.0000x reference)
//
#include <hip/hip_runtime.h>

typedef unsigned short u16;
typedef __attribute__((ext_vector_type(8))) short bf16x8;
typedef __attribute__((ext_vector_type(8))) unsigned short u16x8;
typedef __attribute__((ext_vector_type(4))) float f32x4;

// Problem constants
constexpr int BB = 64;     // batch
constexpr int NN = 256;    // nodes
constexpr int SS = 1024;   // LP*P spatial (= F)
constexpr int FF = 1024;   // node feature dim
constexpr int HH = 512;    // hidden

// EDGE_TYPES = [AB,BA,AC,CA,BC,CB,AA,BB,CC]
// dst A edges {1,3,6}; dst B {0,5,7}; dst C {2,4,8}
__device__ const int d_eArr[3][3] = {{1, 3, 6}, {0, 5, 7}, {2, 4, 8}};
// muCat slot: for src type tp, (dst t) -> e' slot with src(eArr[t][e'])==tp
__device__ const int d_slotE[3][3] = {{2, 0, 0}, {0, 2, 1}, {1, 1, 2}};

__device__ __forceinline__ u16 f2bf(float f) {
    union { float f; unsigned u; } v; v.f = f;
    unsigned r = v.u + 0x7FFFu + ((v.u >> 16) & 1u);
    return (u16)(r >> 16);
}
__device__ __forceinline__ float bf2f(u16 h) {
    union { unsigned u; float f; } v; v.u = ((unsigned)h) << 16;
    return v.f;
}

typedef const __attribute__((address_space(1))) void gv_t;
typedef __attribute__((address_space(3))) void lv_t;
__device__ __forceinline__ void gl16(const void* g, void* l) {
    __builtin_amdgcn_global_load_lds((gv_t*)g, (lv_t*)l, 16, 0, 0);
}
// 16B-slot swizzle per LDS row
__device__ __forceinline__ int swzv(int r) { return (r ^ (r >> 2)) & 3; }

template<int N> __device__ __forceinline__ void waitvm();
template<> __device__ __forceinline__ void waitvm<0>()  { asm volatile("s_waitcnt vmcnt(0)" ::: "memory"); }
template<> __device__ __forceinline__ void waitvm<2>()  { asm volatile("s_waitcnt vmcnt(2)" ::: "memory"); }
template<> __device__ __forceinline__ void waitvm<4>()  { asm volatile("s_waitcnt vmcnt(4)" ::: "memory"); }
template<> __device__ __forceinline__ void waitvm<6>()  { asm volatile("s_waitcnt vmcnt(6)" ::: "memory"); }
template<> __device__ __forceinline__ void waitvm<8>()  { asm volatile("s_waitcnt vmcnt(8)" ::: "memory"); }
template<> __device__ __forceinline__ void waitvm<12>() { asm volatile("s_waitcnt vmcnt(12)" ::: "memory"); }
template<> __device__ __forceinline__ void waitvm<14>() { asm volatile("s_waitcnt vmcnt(14)" ::: "memory"); }
template<> __device__ __forceinline__ void waitvm<16>() { asm volatile("s_waitcnt vmcnt(16)" ::: "memory"); }

__device__ __forceinline__ void lgkm0_bar() {
    asm volatile("s_waitcnt lgkmcnt(0)" ::: "memory");
    __builtin_amdgcn_s_barrier();
}

// G5 grouped-row decode: m-tile g -> global (b*256+n) for local row r (0..127)
__device__ __forceinline__ int g5row(int t, int g, int r) {
    if (t == 0) return (g << 8) + r;
    const int bp = (t == 1) ? (g - 64) : (g - 96);
    const int b  = (bp << 1) + (r >> 6);
    const int n  = ((t == 1) ? 128 : 192) + (r & 63);
    return (b << 8) + n;
}

// ---------------------------------------------------------------------------
// 4-tile software-pipelined 64x64 fp32->bf16 transpose. R15 post-mortem: the
// previous version used __syncthreads(), which lowers to s_waitcnt vmcnt(0)
// before s_barrier and DRAINED the tile-k+1 prefetch every iteration -> fully
// latency-serialized (~2 TB/s invariant). Fix: raw s_barrier + lgkmcnt(0)
// (gemm2's discipline) so the counted-vmcnt prefetch chain is real.
// ---------------------------------------------------------------------------
template<bool STEPR>
__device__ __forceinline__ void tr64p4(const float* __restrict__ in, u16* __restrict__ out,
                                       int ldin, int ldout, int r0, int c0,
                                       float (*tile)[65]) {
    const int col4  = (threadIdx.x & 15) << 2;
    const int rrow  = threadIdx.x >> 4;
    const int dslot = (threadIdx.x & 7) << 3;
    const int crow0 = threadIdx.x >> 3;
    float4 st[2][4];
    auto issue = [&](int slot, int k) {
        const int rr = STEPR ? r0 + k * 64 : r0;
        const int cc = STEPR ? c0 : c0 + k * 64;
#pragma unroll
        for (int p = 0; p < 4; ++p)
            st[slot][p] = *(const float4*)(in + (size_t)(rr + p * 16 + rrow) * ldin + cc + col4);
    };
    issue(0, 0);
#pragma unroll
    for (int k = 0; k < 4; ++k) {
        if (k + 1 < 4) issue((k + 1) & 1, k + 1);
        if (k == 0)      waitvm<4>();     // queue: loads(0), loads(1)
        else if (k == 3) waitvm<2>();     // queue: loads(3), stores(2)
        else             waitvm<6>();     // queue: loads(k), stores(k-1), loads(k+1)
        const int cs = k & 1;
#pragma unroll
        for (int p = 0; p < 4; ++p) {
            const int row = p * 16 + rrow;
            tile[row][col4 + 0] = st[cs][p].x; tile[row][col4 + 1] = st[cs][p].y;
            tile[row][col4 + 2] = st[cs][p].z; tile[row][col4 + 3] = st[cs][p].w;
        }
        lgkm0_bar();                      // my LDS writes done; all waves joined
        const int rr = STEPR ? r0 + k * 64 : r0;
        const int cc = STEPR ? c0 : c0 + k * 64;
#pragma unroll
        for (int p = 0; p < 2; ++p) {
            const int crow = p * 32 + crow0;
            u16x8 w;
#pragma unroll
            for (int j = 0; j < 8; ++j) w[j] = f2bf(tile[dslot + j][crow]);
            *(u16x8*)(out + (size_t)(cc + crow) * ldout + rr + dslot) = w;
        }
        lgkm0_bar();                      // reads consumed (WAR) before next writes
    }
}

// Wsum variant: element = (Wr[e0]+Wr[e1]+Wr[e2])/3, same pipeline (12 loads/tile)
__device__ __forceinline__ void tr64p4sum(const float* __restrict__ s0p,
                                          const float* __restrict__ s1p,
                                          const float* __restrict__ s2p,
                                          u16* __restrict__ out,
                                          int ldin, int ldout, int r0, int c0,
                                          float (*tile)[65]) {
    const int col4  = (threadIdx.x & 15) << 2;
    const int rrow  = threadIdx.x >> 4;
    const int dslot = (threadIdx.x & 7) << 3;
    const int crow0 = threadIdx.x >> 3;
    float4 sa[2][4], sb[2][4], sc[2][4];
    auto issue = [&](int slot, int k) {
        const int rr = r0 + k * 64;       // STEPR-style (r advances)
#pragma unroll
        for (int p = 0; p < 4; ++p) {
            const size_t off = (size_t)(rr + p * 16 + rrow) * ldin + c0 + col4;
            sa[slot][p] = *(const float4*)(s0p + off);
            sb[slot][p] = *(const float4*)(s1p + off);
            sc[slot][p] = *(const float4*)(s2p + off);
        }
    };
    issue(0, 0);
#pragma unroll
    for (int k = 0; k < 4; ++k) {
        if (k + 1 < 4) issue((k + 1) & 1, k + 1);
        if (k == 0)      waitvm<12>();
        else if (k == 3) waitvm<2>();
        else             waitvm<14>();
        const int cs = k & 1;
#pragma unroll
        for (int p = 0; p < 4; ++p) {
            const int row = p * 16 + rrow;
            tile[row][col4 + 0] = (sa[cs][p].x + sb[cs][p].x + sc[cs][p].x) * (1.f / 3.f);
            tile[row][col4 + 1] = (sa[cs][p].y + sb[cs][p].y + sc[cs][p].y) * (1.f / 3.f);
            tile[row][col4 + 2] = (sa[cs][p].z + sb[cs][p].z + sc[cs][p].z) * (1.f / 3.f);
            tile[row][col4 + 3] = (sa[cs][p].w + sb[cs][p].w + sc[cs][p].w) * (1.f / 3.f);
        }
        lgkm0_bar();
        const int rr = r0 + k * 64;
#pragma unroll
        for (int p = 0; p < 2; ++p) {
            const int crow = p * 32 + crow0;
            u16x8 w;
#pragma unroll
            for (int j = 0; j < 8; ++j) w[j] = f2bf(tile[dslot + j][crow]);
            *(u16x8*)(out + (size_t)(c0 + crow) * ldout + rr + dslot) = w;
        }
        lgkm0_bar();
    }
}

// ---------------------------------------------------------------------------
// Combined prep (ONE launch, 1449 blocks, 4 tiles/block pipelined):
// [0,1024) x | +4 W1 | +4 W2 | +32 Wf | +288 WlTc | +96 WsumT | +1 blsum
// ---------------------------------------------------------------------------
__global__ __launch_bounds__(256)
void prep_weights(const float* __restrict__ x,  u16* __restrict__ xT,
                  const float* __restrict__ W1, const float* __restrict__ W2,
                  const float* __restrict__ Wf, const float* __restrict__ Wl,
                  const float* __restrict__ Wr, const float* __restrict__ bl,
                  u16* __restrict__ W1T, u16* __restrict__ W2T, u16* __restrict__ WfT,
                  u16* __restrict__ WlTc, u16* __restrict__ WsumT,
                  float* __restrict__ blsum)
{
    __shared__ float tile[64][65];
    int id = blockIdx.x;
    if (id < 1024) {                       // x[b]: [256 d][1024 s] -> xT[b]: [s][d]
        const int b = id >> 4, rem = id & 15;
        tr64p4<false>(x + (size_t)b * 262144, xT + (size_t)b * 262144,
                      1024, 256, (rem & 3) * 64, (rem >> 2) * 256, tile);
        return;
    }
    id -= 1024;
    if (id < 4) {                          // W1 [256][256] -> W1T
        tr64p4<false>(W1, W1T, 256, 256, id * 64, 0, tile);
        return;
    }
    id -= 4;
    if (id < 4) {                          // W2 [256][256] -> W2T
        tr64p4<false>(W2, W2T, 256, 256, id * 64, 0, tile);
        return;
    }
    id -= 4;
    if (id < 32) {                         // Wf [512 h][1024 f] -> WfT [f][h]
        tr64p4<false>(Wf, WfT, 1024, 512, (id & 7) * 64, (id >> 3) * 256, tile);
        return;
    }
    id -= 32;
    if (id < 288) {                        // WlTc[t][h][e'*1024+f] = Wl[e][f][h]
        const int p = id >> 5, rem = id & 31;        // p in 0..8
        const int t = p / 3, ep = p % 3, e = d_eArr[t][ep];
        tr64p4<true>(Wl + (size_t)e * FF * HH,
                     WlTc + (size_t)t * HH * 3072 + (size_t)ep * 1024,
                     512, 3072, (rem >> 3) * 256, (rem & 7) * 64, tile);
        return;
    }
    id -= 288;
    if (id < 96) {                         // WsumT[t][h][f] = (1/3) sum Wr[e][f][h]
        const int t = id >> 5, rem = id & 31;
        tr64p4sum(Wr + (size_t)d_eArr[t][0] * FF * HH,
                  Wr + (size_t)d_eArr[t][1] * FF * HH,
                  Wr + (size_t)d_eArr[t][2] * FF * HH,
                  WsumT + (size_t)t * HH * FF,
                  512, 1024, (rem >> 3) * 256, (rem & 7) * 64, tile);
        return;
    }
    // blsum (1536), 6 per thread
#pragma unroll
    for (int j = 0; j < 6; ++j) {
        const int idx = j * 256 + threadIdx.x;
        const int t = idx >> 9, hh = idx & 511;
        blsum[t * HH + hh] = bl[d_eArr[t][0] * HH + hh] + bl[d_eArr[t][1] * HH + hh] +
                             bl[d_eArr[t][2] * HH + hh];
    }
}

// ---------------------------------------------------------------------------
// MFMA GEMM core: gl16 staging, NBUF-deep rotating LDS buffers, counted vmcnt,
// LDS-staged fully-coalesced epilogue stores, XCD-locality 1-D grid decode.
// C[M][N] = A[M][K] * (Bt[N][K])^T (+ epilogue).
// EPI: 0 bf16 + aux1[row] | 1 f32 beta partial (direct stores, tiny)
//    | 2 G5 bf16 relu(acc+beta) grouped rows | 3 f32 + aux1[row]
//    | 4 bf16 + aux1[row] + split fused mu (BM=128)
// MODE: 0 1-D grid: b=id&63, kx=id>>6, n0=(kx%NX)*BN, m0=(kx/NX)*BM; A shared
//     | 1 1-D grid: g=id&127, x=id>>7 (G5 grouped rows)
//     | 2 beta K-split (3-D grid: x=n, y=ks, z=t)
// ---------------------------------------------------------------------------
template<int BM, int BN, int KLEN, int EPI, int MODE, int NX, int NBUF>
__global__ __launch_bounds__(256, 2)
void gemm2(const u16* __restrict__ Abase, const u16* __restrict__ Bbase,
           void* __restrict__ Cbase, const float* __restrict__ aux1,
           const float* __restrict__ aux2, u16* __restrict__ muOut,
           long long sB, long long sC, int ldA, int ldB, int ldC)
{
    constexpr int WM = BM / 2, WN = BN / 2;
    constexpr int FM = WM / 16, FN = WN / 16;
    constexpr int NIA = (BM * 4) / 256, NIB = (BN * 4) / 256;
    constexpr int LPS = NIA + NIB;
    constexpr int BUFB = (BM + BN) * 64;
    constexpr int NT = KLEN / 32;
    static_assert(NT >= NBUF, "need >=NBUF K-steps");
    __shared__ __align__(16) unsigned char smem[NBUF * BUFB];
    char* sm = (char*)smem;

    const int tid = threadIdx.x, lane = tid & 63, wave = tid >> 6;
    const int wm = wave >> 1, wn = wave & 1;

    int n0 = 0, m0 = 0, b = 0, t = 0, g = 0;
    const u16* Ab = nullptr; const u16* Bb = nullptr;
    if constexpr (MODE == 0) {
        const int id = blockIdx.x;
        b  = id & 63;
        const int kx = id >> 6;
        n0 = (kx % NX) * BN;
        m0 = (kx / NX) * BM;
        Ab = Abase + (size_t)m0 * ldA;
        Bb = Bbase + (size_t)b * sB + (size_t)n0 * ldB;
    } else if constexpr (MODE == 1) {
        const int id = blockIdx.x;
        g  = id & 127;
        n0 = (id >> 7) * BN;
        t  = (g < 64) ? 0 : (g < 96 ? 1 : 2);
        Ab = Abase;
        Bb = Bbase + (size_t)t * (HH * FF) + (size_t)n0 * ldB;
    } else {                       // MODE 2: z=t, y=ksplit, x=n
        t  = blockIdx.z;
        n0 = blockIdx.x * BN;
        const int k0 = blockIdx.y * KLEN;
        Ab = Abase + (size_t)t * 64 * ldA + k0;
        Bb = Bbase + (size_t)t * (HH * 3072) + (size_t)n0 * ldB + k0;
    }

    // staging addresses: chunk c -> LDS byte c*16 (linear), global src pre-swizzled
    const u16* gAp[NIA]; const u16* gBp[NIB];
    int lAo[NIA], lBo[NIB];
#pragma unroll
    for (int i = 0; i < NIA; ++i) {
        const int c = i * 256 + tid, r = c >> 2, jl = c & 3;
        const int js = jl ^ swzv(r);
        size_t rowoff;
        if constexpr (MODE == 1) rowoff = (size_t)g5row(t, g, r) * FF;
        else                     rowoff = (size_t)r * ldA;
        gAp[i] = Ab + rowoff + js * 8;
        lAo[i] = c * 16;
    }
#pragma unroll
    for (int i = 0; i < NIB; ++i) {
        const int c = i * 256 + tid, r = c >> 2, jl = c & 3;
        gBp[i] = Bb + (size_t)r * ldB + (jl ^ swzv(r)) * 8;
        lBo[i] = BM * 64 + c * 16;
    }
    // fragment read offsets (same swizzle on read side)
    const int q = lane >> 4;
    int rAo[FM], rBo[FN];
#pragma unroll
    for (int i = 0; i < FM; ++i) {
        const int r = wm * WM + i * 16 + (lane & 15);
        rAo[i] = (r * 4 + (q ^ swzv(r))) * 16;
    }
#pragma unroll
    for (int j = 0; j < FN; ++j) {
        const int r = wn * WN + j * 16 + (lane & 15);
        rBo[j] = BM * 64 + (r * 4 + (q ^ swzv(r))) * 16;
    }

    auto stage = [&](int bufo, int it) {
        const int kofs = it * 32;
#pragma unroll
        for (int i = 0; i < NIA; ++i) gl16(gAp[i] + kofs, sm + bufo + lAo[i]);
#pragma unroll
        for (int i = 0; i < NIB; ++i) gl16(gBp[i] + kofs, sm + bufo + lBo[i]);
    };

    const f32x4 zero4 = {0.f, 0.f, 0.f, 0.f};
    f32x4 acc[FM][FN];
#pragma unroll
    for (int i = 0; i < FM; ++i)
#pragma unroll
        for (int j = 0; j < FN; ++j) acc[i][j] = zero4;

#pragma unroll
    for (int pb = 0; pb < NBUF; ++pb) stage(pb * BUFB, pb);

    int bufo = 0;
    for (int it = 0; it < NT; ++it) {
        const int rem = NT - 1 - it;       // tiles staged beyond `it`
        if (rem >= 2)      waitvm<2 * LPS>();
        else if (rem == 1) waitvm<LPS>();
        else               waitvm<0>();
        __builtin_amdgcn_s_barrier();

        bf16x8 af[FM], bq[FN];
#pragma unroll
        for (int i = 0; i < FM; ++i) af[i] = *(const bf16x8*)(sm + bufo + rAo[i]);
#pragma unroll
        for (int j = 0; j < FN; ++j) bq[j] = *(const bf16x8*)(sm + bufo + rBo[j]);
        asm volatile("s_waitcnt lgkmcnt(0)" ::: "memory");
        __builtin_amdgcn_sched_barrier(0);

        __builtin_amdgcn_s_setprio(1);
#pragma unroll
        for (int i = 0; i < FM; ++i)
#pragma unroll
            for (int j = 0; j < FN; ++j)
                acc[i][j] = __builtin_amdgcn_mfma_f32_16x16x32_bf16(af[i], bq[j], acc[i][j], 0, 0, 0);
        __builtin_amdgcn_s_setprio(0);

        __builtin_amdgcn_s_barrier();
        if (it + NBUF < NT) stage(bufo, it + NBUF);
        bufo = (bufo == (NBUF - 1) * BUFB) ? 0 : bufo + BUFB;
    }
    // after the final barrier above, all waves are done with LDS -> reuse it

    // ---------------- epilogue ----------------
    const int q4 = q << 2;
    constexpr int BNP = BN + 8;           // padded LDS row stride (elements)

    if constexpr (EPI == 1) {             // beta partials (tiny): direct stores
        float* C = (float*)Cbase + (size_t)blockIdx.y * 98304 + (size_t)t * (64 * HH);
        const int colb = n0 + wn * WN + (lane & 15);
#pragma unroll
        for (int i = 0; i < FM; ++i)
#pragma unroll
            for (int rr = 0; rr < 4; ++rr) {
                const int row = wm * WM + i * 16 + q4 + rr;
#pragma unroll
                for (int j = 0; j < FN; ++j)
                    C[(size_t)row * HH + colb + j * 16] = acc[i][j][rr];
            }
    } else if constexpr (EPI == 0 || EPI == 2) {   // bf16 tile via LDS
        u16* lds = (u16*)sm;              // [BM][BNP] u16
        const int lcb = wn * WN + (lane & 15);
        float bet[FN];
        if constexpr (EPI == 2) {         // beta per (t, b(row-block), abs col)
            const int bb = (t == 0) ? g : ((((t == 1) ? (g - 64) : (g - 96)) << 1) + wm);
#pragma unroll
            for (int j = 0; j < FN; ++j) {
                const int col = n0 + lcb + j * 16;
                float s = aux2[t * HH + col];
#pragma unroll
                for (int ks = 0; ks < 8; ++ks)
                    s += aux1[(size_t)ks * 98304 + (size_t)((t << 6) + bb) * HH + col];
                bet[j] = s * (1.f / 3.f);
            }
        }
#pragma unroll
        for (int i = 0; i < FM; ++i)
#pragma unroll
            for (int rr = 0; rr < 4; ++rr) {
                const int lrow = wm * WM + i * 16 + q4 + rr;
                float bias = 0.f;
                if constexpr (EPI == 0) bias = aux1[m0 + lrow];
#pragma unroll
                for (int j = 0; j < FN; ++j) {
                    float v = acc[i][j][rr] + ((EPI == 2) ? bet[j] : bias);
                    if constexpr (EPI == 2) v = fmaxf(v, 0.f);
                    lds[lrow * BNP + lcb + j * 16] = f2bf(v);
                }
            }
        __syncthreads();
        {
            u16* Cg;
            if constexpr (EPI == 2) Cg = (u16*)Cbase;
            else                    Cg = (u16*)Cbase + (size_t)b * sC;
            constexpr int CH = (BM * BN) / (256 * 8);
#pragma unroll
            for (int c = 0; c < CH; ++c) {
                const int e   = (c * 256 + tid) * 8;
                const int row = e / BN, col = e % BN;
                const bf16x8 v = *(const bf16x8*)&lds[row * BNP + col];
                size_t goff;
                if constexpr (EPI == 2) goff = (size_t)g5row(t, g, row) * ldC + n0 + col;
                else                    goff = (size_t)(m0 + row) * ldC + n0 + col;
                *(bf16x8*)(Cg + goff) = v;
            }
        }
    } else if constexpr (EPI == 4) {      // bf16 + bias + split fused mu (BM=128)
        u16* lds = (u16*)sm;              // [128][BNP] u16
        float* mubuf = (float*)(sm + 128 * BNP * 2);   // [2 wm][BN] f32
        const int lcb = wn * WN + (lane & 15);
        float t0[FN];
#pragma unroll
        for (int j = 0; j < FN; ++j) t0[j] = 0.f;
#pragma unroll
        for (int i = 0; i < FM; ++i)
#pragma unroll
            for (int rr = 0; rr < 4; ++rr) {
                const int lrow = wm * WM + i * 16 + q4 + rr;
                const float bias = aux1[m0 + lrow];
#pragma unroll
                for (int j = 0; j < FN; ++j) {
                    const float v = acc[i][j][rr] + bias;
                    lds[lrow * BNP + lcb + j * 16] = f2bf(v);
                    t0[j] += v;
                }
            }
#pragma unroll
        for (int j = 0; j < FN; ++j) {    // reduce across q-groups (16 rows -> 64)
            t0[j] += __shfl_xor(t0[j], 16, 64);
            t0[j] += __shfl_xor(t0[j], 32, 64);
        }
        if (m0 == 0 && lane < 16) {       // stash per-wm partial for type A
#pragma unroll
            for (int j = 0; j < FN; ++j)
                mubuf[wm * BN + lcb + j * 16] = t0[j];
        }
        __syncthreads();
        {   // coalesced h-tile store
            u16* Cg = (u16*)Cbase + (size_t)b * sC;
            constexpr int CH = (BM * BN) / (256 * 8);
#pragma unroll
            for (int c = 0; c < CH; ++c) {
                const int e   = (c * 256 + tid) * 8;
                const int row = e / BN, col = e % BN;
                const bf16x8 v = *(const bf16x8*)&lds[row * BNP + col];
                *(bf16x8*)(Cg + (size_t)(m0 + row) * ldC + n0 + col) = v;
            }
        }
        if (m0 == 0) {                    // type A: combine wm0+wm1, /128
            if (wm == 0 && lane < 16) {
#pragma unroll
                for (int j = 0; j < FN; ++j) {
                    const int lcol = lcb + j * 16;
                    const int col  = n0 + lcol;
                    const u16 v = f2bf((mubuf[lcol] + mubuf[BN + lcol]) * (1.f / 128.f));
#pragma unroll
                    for (int tt = 0; tt < 3; ++tt)
                        muOut[((size_t)tt * BB + b) * 3072 + (size_t)d_slotE[0][tt] * 1024 + col] = v;
                }
            }
        } else {                          // m0=128: wm0 = type B, wm1 = type C
            if (lane < 16) {
                const int tp = 1 + wm;
#pragma unroll
                for (int j = 0; j < FN; ++j) {
                    const int col = n0 + lcb + j * 16;
                    const u16 v = f2bf(t0[j] * (1.f / 64.f));
#pragma unroll
                    for (int tt = 0; tt < 3; ++tt)
                        muOut[((size_t)tt * BB + b) * 3072 + (size_t)d_slotE[tp][tt] * 1024 + col] = v;
                }
            }
        }
    } else {                              // EPI 3: f32 tile via LDS, two halves
        float* lf = (float*)sm;           // [BM/2][BNP] f32
        float* Cg = (float*)Cbase + (size_t)b * sC;
        const int lcb = wn * WN + (lane & 15);
#pragma unroll
        for (int half = 0; half < 2; ++half) {
            if (wm == half) {
#pragma unroll
                for (int i = 0; i < FM; ++i)
#pragma unroll
                    for (int rr = 0; rr < 4; ++rr) {
                        const int lrow = i * 16 + q4 + rr;               // 0..WM-1
                        const float bias = aux1[m0 + half * WM + lrow];
#pragma unroll
                        for (int j = 0; j < FN; ++j)
                            lf[lrow * BNP + lcb + j * 16] = acc[i][j][rr] + bias;
                    }
            }
            __syncthreads();
            constexpr int CH = (WM * BN) / (256 * 4);
#pragma unroll
            for (int c = 0; c < CH; ++c) {
                const int e   = (c * 256 + tid) * 4;
                const int row = e / BN, col = e % BN;
                const f32x4 v = *(const f32x4*)&lf[row * BNP + col];
                *(f32x4*)(Cg + (size_t)(m0 + half * WM + row) * ldC + n0 + col) = v;
            }
            __syncthreads();
        }
    }
}

// ---------------------------------------------------------------------------
extern "C" void kernel_launch(void* const* d_in, const int* in_sizes, int n_in,
                              void* d_out, int out_size, void* d_ws, size_t ws_size,
                              hipStream_t stream) {
    const float* x  = (const float*)d_in[0];
    const float* W1 = (const float*)d_in[1];
    const float* b1 = (const float*)d_in[2];
    const float* Wl = (const float*)d_in[3];
    const float* bl = (const float*)d_in[4];
    const float* Wr = (const float*)d_in[5];
    const float* Wf = (const float*)d_in[6];
    const float* bf = (const float*)d_in[7];
    const float* W2 = (const float*)d_in[8];
    const float* b2 = (const float*)d_in[9];
    float* y = (float*)d_out;

    // workspace layout (u16 elements)
    u16* wsS   = (u16*)d_ws;
    u16* xT    = wsS;                       // [64][1024][256] = 16,777,216
    u16* h     = wsS + 16777216;            // [64][256][1024] = 16,777,216
    u16* r     = wsS + 33554432;            // [64][256][512]  =  8,388,608
    u16* W1T   = wsS + 41943040;            // [256][256]
    u16* W2T   = wsS + 42008576;            // [256][256]
    u16* WfT   = wsS + 42074112;            // [1024][512]
    u16* WsumT = wsS + 42598400;            // [3][512][1024]
    u16* WlTc  = wsS + 44171264;            // [3][512][3072]
    u16* muCat = wsS + 48889856;            // [3][64][3072]
    float* tmp8  = (float*)(wsS + 49479680);  // [8][3][64][512] f32
    float* blsum = tmp8 + 786432;             // [3][512] f32
    u16* outT = xT;                           // alias: xT dead after G1

    // prep: x-transpose + all weight prep, ONE launch, pipelined (raw barriers)
    prep_weights<<<dim3(1449), 256, 0, stream>>>(x, xT, W1, W2, Wf, Wl, Wr, bl,
                                                 W1T, W2T, WfT, WlTc, WsumT, blsum);

    // G1: h[b][n][s] = W1T[n][d] . xT[b][s][d] + b1[n], split fused mu -> muCat
    gemm2<128, 256, 256, 4, 0, 4, 3><<<dim3(512), 256, 0, stream>>>(
        W1T, xT, h, b1, nullptr, muCat, 262144, 262144, 256, 256, 1024);
    // beta partials: tmp8[ks][t][b][h] = muCat[t][b][kslice] . WlTc[t][h][kslice]
    gemm2<64, 64, 384, 1, 2, 1, 3><<<dim3(8, 8, 3), 256, 0, stream>>>(
        muCat, WlTc, tmp8, nullptr, nullptr, nullptr, 0, 0, 3072, 3072, 512);
    // G5: r[b*256+n][h] = relu( h-rows . WsumT[t(n)] + beta ), grouped rows
    gemm2<128, 128, 1024, 2, 1, 4, 3><<<dim3(512), 256, 0, stream>>>(
        h, WsumT, r, tmp8, blsum, nullptr, 0, 0, 1024, 1024, 512);
    // G6: outT[b][f][n] = WfT[f][:] . r[b][n][:] + bf[f]
    gemm2<256, 128, 512, 0, 0, 2, 3><<<dim3(512), 256, 0, stream>>>(
        WfT, r, outT, bf, nullptr, nullptr, 131072, 262144, 512, 512, 256);
    // G7: y[b][d][s] = W2T[d][:] . outT[b][s][:] + b2[d]
    gemm2<256, 128, 256, 3, 0, 8, 3><<<dim3(512), 256, 0, stream>>>(
        W2T, outT, y, b2, nullptr, nullptr, 262144, 262144, 256, 256, 1024);
}

// Round 17
// 126.793 us; speedup vs baseline: 1.0256x; 1.0256x over previous
//
#include <hip/hip_runtime.h>

typedef unsigned short u16;
typedef __attribute__((ext_vector_type(8))) short bf16x8;
typedef __attribute__((ext_vector_type(8))) unsigned short u16x8;
typedef __attribute__((ext_vector_type(4))) float f32x4;

// Problem constants
constexpr int BB = 64;     // batch
constexpr int NN = 256;    // nodes
constexpr int SS = 1024;   // LP*P spatial (= F)
constexpr int FF = 1024;   // node feature dim
constexpr int HH = 512;    // hidden

// EDGE_TYPES = [AB,BA,AC,CA,BC,CB,AA,BB,CC]
// dst A edges {1,3,6}; dst B {0,5,7}; dst C {2,4,8}
__device__ const int d_eArr[3][3] = {{1, 3, 6}, {0, 5, 7}, {2, 4, 8}};
// muCat slot: for src type tp, (dst t) -> e' slot with src(eArr[t][e'])==tp
__device__ const int d_slotE[3][3] = {{2, 0, 0}, {0, 2, 1}, {1, 1, 2}};

__device__ __forceinline__ u16 f2bf(float f) {
    union { float f; unsigned u; } v; v.f = f;
    unsigned r = v.u + 0x7FFFu + ((v.u >> 16) & 1u);
    return (u16)(r >> 16);
}
__device__ __forceinline__ float bf2f(u16 h) {
    union { unsigned u; float f; } v; v.u = ((unsigned)h) << 16;
    return v.f;
}

typedef const __attribute__((address_space(1))) void gv_t;
typedef __attribute__((address_space(3))) void lv_t;
__device__ __forceinline__ void gl16(const void* g, void* l) {
    __builtin_amdgcn_global_load_lds((gv_t*)g, (lv_t*)l, 16, 0, 0);
}
// 16B-slot swizzle per LDS row
__device__ __forceinline__ int swzv(int r) { return (r ^ (r >> 2)) & 3; }

template<int N> __device__ __forceinline__ void waitvm();
template<> __device__ __forceinline__ void waitvm<0>()  { asm volatile("s_waitcnt vmcnt(0)" ::: "memory"); }
template<> __device__ __forceinline__ void waitvm<2>()  { asm volatile("s_waitcnt vmcnt(2)" ::: "memory"); }
template<> __device__ __forceinline__ void waitvm<4>()  { asm volatile("s_waitcnt vmcnt(4)" ::: "memory"); }
template<> __device__ __forceinline__ void waitvm<6>()  { asm volatile("s_waitcnt vmcnt(6)" ::: "memory"); }
template<> __device__ __forceinline__ void waitvm<8>()  { asm volatile("s_waitcnt vmcnt(8)" ::: "memory"); }
template<> __device__ __forceinline__ void waitvm<12>() { asm volatile("s_waitcnt vmcnt(12)" ::: "memory"); }
template<> __device__ __forceinline__ void waitvm<14>() { asm volatile("s_waitcnt vmcnt(14)" ::: "memory"); }
template<> __device__ __forceinline__ void waitvm<16>() { asm volatile("s_waitcnt vmcnt(16)" ::: "memory"); }

// G5 grouped-row decode: m-tile g -> global (b*256+n) for local row r (0..127)
__device__ __forceinline__ int g5row(int t, int g, int r) {
    if (t == 0) return (g << 8) + r;
    const int bp = (t == 1) ? (g - 64) : (g - 96);
    const int b  = (bp << 1) + (r >> 6);
    const int n  = ((t == 1) ? 128 : 192) + (r & 63);
    return (b << 8) + n;
}

// ---------------------------------------------------------------------------
// 64x64 fp32->bf16 transpose tile with full-128B-line writes. One tile per
// block (5793 blocks): measured fastest prep variant (R14, 46-50 us; the
// pipelined 4-tile variants R15/R16 were ~2-5 us slower; ~2 TB/s invariant
// across all structures -> prep treated as converged).
// ---------------------------------------------------------------------------
__device__ __forceinline__ void tr64(const float* __restrict__ in, u16* __restrict__ out,
                                     int ldin, int ldout, int r0, int c0,
                                     float (*tile)[65]) {
    const int col4 = (threadIdx.x & 15) << 2;    // 0..60
    const int rrow = threadIdx.x >> 4;           // 0..15
#pragma unroll
    for (int p = 0; p < 4; ++p) {
        const int row = p * 16 + rrow;
        const float4 v = *(const float4*)(in + (size_t)(r0 + row) * ldin + c0 + col4);
        tile[row][col4 + 0] = v.x; tile[row][col4 + 1] = v.y;
        tile[row][col4 + 2] = v.z; tile[row][col4 + 3] = v.w;
    }
    __syncthreads();
    const int dslot = (threadIdx.x & 7) << 3;    // 0,8,..,56
    const int crow0 = threadIdx.x >> 3;          // 0..31
#pragma unroll
    for (int p = 0; p < 2; ++p) {
        const int crow = p * 32 + crow0;
        u16x8 w;
#pragma unroll
        for (int j = 0; j < 8; ++j) w[j] = f2bf(tile[dslot + j][crow]);
        *(u16x8*)(out + (size_t)(c0 + crow) * ldout + r0 + dslot) = w;
    }
    __syncthreads();
}

// Wsum variant: same geometry, element = (Wr[e0]+Wr[e1]+Wr[e2])/3
__device__ __forceinline__ void tr64sum(const float* __restrict__ s0p,
                                        const float* __restrict__ s1p,
                                        const float* __restrict__ s2p,
                                        u16* __restrict__ out,
                                        int ldin, int ldout, int r0, int c0,
                                        float (*tile)[65]) {
    const int col4 = (threadIdx.x & 15) << 2;
    const int rrow = threadIdx.x >> 4;
#pragma unroll
    for (int p = 0; p < 4; ++p) {
        const int row = p * 16 + rrow;
        const size_t off = (size_t)(r0 + row) * ldin + c0 + col4;
        const float4 a = *(const float4*)(s0p + off);
        const float4 b = *(const float4*)(s1p + off);
        const float4 c = *(const float4*)(s2p + off);
        tile[row][col4 + 0] = (a.x + b.x + c.x) * (1.f / 3.f);
        tile[row][col4 + 1] = (a.y + b.y + c.y) * (1.f / 3.f);
        tile[row][col4 + 2] = (a.z + b.z + c.z) * (1.f / 3.f);
        tile[row][col4 + 3] = (a.w + b.w + c.w) * (1.f / 3.f);
    }
    __syncthreads();
    const int dslot = (threadIdx.x & 7) << 3;
    const int crow0 = threadIdx.x >> 3;
#pragma unroll
    for (int p = 0; p < 2; ++p) {
        const int crow = p * 32 + crow0;
        u16x8 w;
#pragma unroll
        for (int j = 0; j < 8; ++j) w[j] = f2bf(tile[dslot + j][crow]);
        *(u16x8*)(out + (size_t)(c0 + crow) * ldout + r0 + dslot) = w;
    }
    __syncthreads();
}

// ---------------------------------------------------------------------------
// Combined prep (ONE launch): x-transpose + W1T/W2T/WfT + WlTcat + WsumT + blsum
// Block map: [0,4096) x | +16 W1 | +16 W2 | +128 Wf | +1152 WlTc | +384 WsumT | +1 blsum
// ---------------------------------------------------------------------------
__global__ __launch_bounds__(256)
void prep_weights(const float* __restrict__ x,  u16* __restrict__ xT,
                  const float* __restrict__ W1, const float* __restrict__ W2,
                  const float* __restrict__ Wf, const float* __restrict__ Wl,
                  const float* __restrict__ Wr, const float* __restrict__ bl,
                  u16* __restrict__ W1T, u16* __restrict__ W2T, u16* __restrict__ WfT,
                  u16* __restrict__ WlTc, u16* __restrict__ WsumT,
                  float* __restrict__ blsum)
{
    __shared__ float tile[64][65];
    int id = blockIdx.x;
    if (id < 4096) {                       // x[b]: [256 d][1024 s] -> xT[b]: [s][d]
        const int b = id >> 6, rem = id & 63;
        tr64(x + (size_t)b * 262144, xT + (size_t)b * 262144,
             1024, 256, (rem & 3) * 64, (rem >> 2) * 64, tile);
        return;
    }
    id -= 4096;
    if (id < 16) {                         // W1 [256][256] -> W1T
        tr64(W1, W1T, 256, 256, (id & 3) * 64, (id >> 2) * 64, tile);
        return;
    }
    id -= 16;
    if (id < 16) {                         // W2 [256][256] -> W2T
        tr64(W2, W2T, 256, 256, (id & 3) * 64, (id >> 2) * 64, tile);
        return;
    }
    id -= 16;
    if (id < 128) {                        // Wf [512 h][1024 f] -> WfT [f][h]
        tr64(Wf, WfT, 1024, 512, (id & 7) * 64, (id >> 3) * 64, tile);
        return;
    }
    id -= 128;
    if (id < 1152) {                       // WlTc[t][h][e'*1024+f] = Wl[e][f][h]
        const int p = id >> 7, rem = id & 127;        // p in 0..8
        const int t = p / 3, ep = p % 3, e = d_eArr[t][ep];
        tr64(Wl + (size_t)e * FF * HH, WlTc + (size_t)t * HH * 3072 + (size_t)ep * 1024,
             512, 3072, (rem & 15) * 64, (rem >> 4) * 64, tile);
        return;
    }
    id -= 1152;
    if (id < 384) {                        // WsumT[t][h][f] = (1/3) sum Wr[e][f][h]
        const int t = id >> 7, rem = id & 127;
        tr64sum(Wr + (size_t)d_eArr[t][0] * FF * HH,
                Wr + (size_t)d_eArr[t][1] * FF * HH,
                Wr + (size_t)d_eArr[t][2] * FF * HH,
                WsumT + (size_t)t * HH * FF,
                512, 1024, (rem & 15) * 64, (rem >> 4) * 64, tile);
        return;
    }
    // blsum (1536), 6 per thread
#pragma unroll
    for (int j = 0; j < 6; ++j) {
        const int idx = j * 256 + threadIdx.x;
        const int t = idx >> 9, hh = idx & 511;
        blsum[t * HH + hh] = bl[d_eArr[t][0] * HH + hh] + bl[d_eArr[t][1] * HH + hh] +
                             bl[d_eArr[t][2] * HH + hh];
    }
}

// ---------------------------------------------------------------------------
// MFMA GEMM core: gl16 staging, NBUF-deep rotating LDS buffers, counted vmcnt,
// LDS-staged fully-coalesced epilogue stores, XCD-locality 1-D grid decode.
// C[M][N] = A[M][K] * (Bt[N][K])^T (+ epilogue).
// EPI: 0 bf16 + aux1[row] | 1 f32 beta partial (direct stores, tiny)
//    | 2 G5 bf16 relu(acc+beta) grouped rows | 3 f32 + aux1[row]
//    | 4 bf16 + aux1[row] + split fused mu (BM=128)
// MODE: 0 1-D grid: b=id&63, kx=id>>6, n0=(kx%NX)*BN, m0=(kx/NX)*BM; A shared
//     | 1 1-D grid: g=id&127, x=id>>7 (G5 grouped rows)
//     | 2 beta K-split (3-D grid: x=n, y=ks, z=t)
// ---------------------------------------------------------------------------
template<int BM, int BN, int KLEN, int EPI, int MODE, int NX, int NBUF>
__global__ __launch_bounds__(256, 2)
void gemm2(const u16* __restrict__ Abase, const u16* __restrict__ Bbase,
           void* __restrict__ Cbase, const float* __restrict__ aux1,
           const float* __restrict__ aux2, u16* __restrict__ muOut,
           long long sB, long long sC, int ldA, int ldB, int ldC)
{
    constexpr int WM = BM / 2, WN = BN / 2;
    constexpr int FM = WM / 16, FN = WN / 16;
    constexpr int NIA = (BM * 4) / 256, NIB = (BN * 4) / 256;
    constexpr int LPS = NIA + NIB;
    constexpr int BUFB = (BM + BN) * 64;
    constexpr int NT = KLEN / 32;
    static_assert(NT >= NBUF, "need >=NBUF K-steps");
    __shared__ __align__(16) unsigned char smem[NBUF * BUFB];
    char* sm = (char*)smem;

    const int tid = threadIdx.x, lane = tid & 63, wave = tid >> 6;
    const int wm = wave >> 1, wn = wave & 1;

    int n0 = 0, m0 = 0, b = 0, t = 0, g = 0;
    const u16* Ab = nullptr; const u16* Bb = nullptr;
    if constexpr (MODE == 0) {
        const int id = blockIdx.x;
        b  = id & 63;
        const int kx = id >> 6;
        n0 = (kx % NX) * BN;
        m0 = (kx / NX) * BM;
        Ab = Abase + (size_t)m0 * ldA;
        Bb = Bbase + (size_t)b * sB + (size_t)n0 * ldB;
    } else if constexpr (MODE == 1) {
        const int id = blockIdx.x;
        g  = id & 127;
        n0 = (id >> 7) * BN;
        t  = (g < 64) ? 0 : (g < 96 ? 1 : 2);
        Ab = Abase;
        Bb = Bbase + (size_t)t * (HH * FF) + (size_t)n0 * ldB;
    } else {                       // MODE 2: z=t, y=ksplit, x=n
        t  = blockIdx.z;
        n0 = blockIdx.x * BN;
        const int k0 = blockIdx.y * KLEN;
        Ab = Abase + (size_t)t * 64 * ldA + k0;
        Bb = Bbase + (size_t)t * (HH * 3072) + (size_t)n0 * ldB + k0;
    }

    // staging addresses: chunk c -> LDS byte c*16 (linear), global src pre-swizzled
    const u16* gAp[NIA]; const u16* gBp[NIB];
    int lAo[NIA], lBo[NIB];
#pragma unroll
    for (int i = 0; i < NIA; ++i) {
        const int c = i * 256 + tid, r = c >> 2, jl = c & 3;
        const int js = jl ^ swzv(r);
        size_t rowoff;
        if constexpr (MODE == 1) rowoff = (size_t)g5row(t, g, r) * FF;
        else                     rowoff = (size_t)r * ldA;
        gAp[i] = Ab + rowoff + js * 8;
        lAo[i] = c * 16;
    }
#pragma unroll
    for (int i = 0; i < NIB; ++i) {
        const int c = i * 256 + tid, r = c >> 2, jl = c & 3;
        gBp[i] = Bb + (size_t)r * ldB + (jl ^ swzv(r)) * 8;
        lBo[i] = BM * 64 + c * 16;
    }
    // fragment read offsets (same swizzle on read side)
    const int q = lane >> 4;
    int rAo[FM], rBo[FN];
#pragma unroll
    for (int i = 0; i < FM; ++i) {
        const int r = wm * WM + i * 16 + (lane & 15);
        rAo[i] = (r * 4 + (q ^ swzv(r))) * 16;
    }
#pragma unroll
    for (int j = 0; j < FN; ++j) {
        const int r = wn * WN + j * 16 + (lane & 15);
        rBo[j] = BM * 64 + (r * 4 + (q ^ swzv(r))) * 16;
    }

    auto stage = [&](int bufo, int it) {
        const int kofs = it * 32;
#pragma unroll
        for (int i = 0; i < NIA; ++i) gl16(gAp[i] + kofs, sm + bufo + lAo[i]);
#pragma unroll
        for (int i = 0; i < NIB; ++i) gl16(gBp[i] + kofs, sm + bufo + lBo[i]);
    };

    const f32x4 zero4 = {0.f, 0.f, 0.f, 0.f};
    f32x4 acc[FM][FN];
#pragma unroll
    for (int i = 0; i < FM; ++i)
#pragma unroll
        for (int j = 0; j < FN; ++j) acc[i][j] = zero4;

#pragma unroll
    for (int pb = 0; pb < NBUF; ++pb) stage(pb * BUFB, pb);

    int bufo = 0;
    for (int it = 0; it < NT; ++it) {
        const int rem = NT - 1 - it;       // tiles staged beyond `it`
        if (rem >= 2)      waitvm<2 * LPS>();
        else if (rem == 1) waitvm<LPS>();
        else               waitvm<0>();
        __builtin_amdgcn_s_barrier();

        bf16x8 af[FM], bq[FN];
#pragma unroll
        for (int i = 0; i < FM; ++i) af[i] = *(const bf16x8*)(sm + bufo + rAo[i]);
#pragma unroll
        for (int j = 0; j < FN; ++j) bq[j] = *(const bf16x8*)(sm + bufo + rBo[j]);
        asm volatile("s_waitcnt lgkmcnt(0)" ::: "memory");
        __builtin_amdgcn_sched_barrier(0);

        __builtin_amdgcn_s_setprio(1);
#pragma unroll
        for (int i = 0; i < FM; ++i)
#pragma unroll
            for (int j = 0; j < FN; ++j)
                acc[i][j] = __builtin_amdgcn_mfma_f32_16x16x32_bf16(af[i], bq[j], acc[i][j], 0, 0, 0);
        __builtin_amdgcn_s_setprio(0);

        __builtin_amdgcn_s_barrier();
        if (it + NBUF < NT) stage(bufo, it + NBUF);
        bufo = (bufo == (NBUF - 1) * BUFB) ? 0 : bufo + BUFB;
    }
    // after the final barrier above, all waves are done with LDS -> reuse it

    // ---------------- epilogue ----------------
    const int q4 = q << 2;
    constexpr int BNP = BN + 8;           // padded LDS row stride (elements)

    if constexpr (EPI == 1) {             // beta partials (tiny): direct stores
        float* C = (float*)Cbase + (size_t)blockIdx.y * 98304 + (size_t)t * (64 * HH);
        const int colb = n0 + wn * WN + (lane & 15);
#pragma unroll
        for (int i = 0; i < FM; ++i)
#pragma unroll
            for (int rr = 0; rr < 4; ++rr) {
                const int row = wm * WM + i * 16 + q4 + rr;
#pragma unroll
                for (int j = 0; j < FN; ++j)
                    C[(size_t)row * HH + colb + j * 16] = acc[i][j][rr];
            }
    } else if constexpr (EPI == 0 || EPI == 2) {   // bf16 tile via LDS
        u16* lds = (u16*)sm;              // [BM][BNP] u16
        const int lcb = wn * WN + (lane & 15);
        float bet[FN];
        if constexpr (EPI == 2) {         // beta per (t, b(row-block), abs col)
            const int bb = (t == 0) ? g : ((((t == 1) ? (g - 64) : (g - 96)) << 1) + wm);
#pragma unroll
            for (int j = 0; j < FN; ++j) {
                const int col = n0 + lcb + j * 16;
                float s = aux2[t * HH + col];
#pragma unroll
                for (int ks = 0; ks < 8; ++ks)
                    s += aux1[(size_t)ks * 98304 + (size_t)((t << 6) + bb) * HH + col];
                bet[j] = s * (1.f / 3.f);
            }
        }
#pragma unroll
        for (int i = 0; i < FM; ++i)
#pragma unroll
            for (int rr = 0; rr < 4; ++rr) {
                const int lrow = wm * WM + i * 16 + q4 + rr;
                float bias = 0.f;
                if constexpr (EPI == 0) bias = aux1[m0 + lrow];
#pragma unroll
                for (int j = 0; j < FN; ++j) {
                    float v = acc[i][j][rr] + ((EPI == 2) ? bet[j] : bias);
                    if constexpr (EPI == 2) v = fmaxf(v, 0.f);
                    lds[lrow * BNP + lcb + j * 16] = f2bf(v);
                }
            }
        __syncthreads();
        {
            u16* Cg;
            if constexpr (EPI == 2) Cg = (u16*)Cbase;
            else                    Cg = (u16*)Cbase + (size_t)b * sC;
            constexpr int CH = (BM * BN) / (256 * 8);
#pragma unroll
            for (int c = 0; c < CH; ++c) {
                const int e   = (c * 256 + tid) * 8;
                const int row = e / BN, col = e % BN;
                const bf16x8 v = *(const bf16x8*)&lds[row * BNP + col];
                size_t goff;
                if constexpr (EPI == 2) goff = (size_t)g5row(t, g, row) * ldC + n0 + col;
                else                    goff = (size_t)(m0 + row) * ldC + n0 + col;
                *(bf16x8*)(Cg + goff) = v;
            }
        }
    } else if constexpr (EPI == 4) {      // bf16 + bias + split fused mu (BM=128)
        u16* lds = (u16*)sm;              // [128][BNP] u16
        float* mubuf = (float*)(sm + 128 * BNP * 2);   // [2 wm][BN] f32
        const int lcb = wn * WN + (lane & 15);
        float t0[FN];
#pragma unroll
        for (int j = 0; j < FN; ++j) t0[j] = 0.f;
#pragma unroll
        for (int i = 0; i < FM; ++i)
#pragma unroll
            for (int rr = 0; rr < 4; ++rr) {
                const int lrow = wm * WM + i * 16 + q4 + rr;
                const float bias = aux1[m0 + lrow];
#pragma unroll
                for (int j = 0; j < FN; ++j) {
                    const float v = acc[i][j][rr] + bias;
                    lds[lrow * BNP + lcb + j * 16] = f2bf(v);
                    t0[j] += v;
                }
            }
#pragma unroll
        for (int j = 0; j < FN; ++j) {    // reduce across q-groups (16 rows -> 64)
            t0[j] += __shfl_xor(t0[j], 16, 64);
            t0[j] += __shfl_xor(t0[j], 32, 64);
        }
        if (m0 == 0 && lane < 16) {       // stash per-wm partial for type A
#pragma unroll
            for (int j = 0; j < FN; ++j)
                mubuf[wm * BN + lcb + j * 16] = t0[j];
        }
        __syncthreads();
        {   // coalesced h-tile store
            u16* Cg = (u16*)Cbase + (size_t)b * sC;
            constexpr int CH = (BM * BN) / (256 * 8);
#pragma unroll
            for (int c = 0; c < CH; ++c) {
                const int e   = (c * 256 + tid) * 8;
                const int row = e / BN, col = e % BN;
                const bf16x8 v = *(const bf16x8*)&lds[row * BNP + col];
                *(bf16x8*)(Cg + (size_t)(m0 + row) * ldC + n0 + col) = v;
            }
        }
        if (m0 == 0) {                    // type A: combine wm0+wm1, /128
            if (wm == 0 && lane < 16) {
#pragma unroll
                for (int j = 0; j < FN; ++j) {
                    const int lcol = lcb + j * 16;
                    const int col  = n0 + lcol;
                    const u16 v = f2bf((mubuf[lcol] + mubuf[BN + lcol]) * (1.f / 128.f));
#pragma unroll
                    for (int tt = 0; tt < 3; ++tt)
                        muOut[((size_t)tt * BB + b) * 3072 + (size_t)d_slotE[0][tt] * 1024 + col] = v;
                }
            }
        } else {                          // m0=128: wm0 = type B, wm1 = type C
            if (lane < 16) {
                const int tp = 1 + wm;
#pragma unroll
                for (int j = 0; j < FN; ++j) {
                    const int col = n0 + lcb + j * 16;
                    const u16 v = f2bf(t0[j] * (1.f / 64.f));
#pragma unroll
                    for (int tt = 0; tt < 3; ++tt)
                        muOut[((size_t)tt * BB + b) * 3072 + (size_t)d_slotE[tp][tt] * 1024 + col] = v;
                }
            }
        }
    } else {                              // EPI 3: f32 tile via LDS, two halves
        float* lf = (float*)sm;           // [BM/2][BNP] f32
        float* Cg = (float*)Cbase + (size_t)b * sC;
        const int lcb = wn * WN + (lane & 15);
#pragma unroll
        for (int half = 0; half < 2; ++half) {
            if (wm == half) {
#pragma unroll
                for (int i = 0; i < FM; ++i)
#pragma unroll
                    for (int rr = 0; rr < 4; ++rr) {
                        const int lrow = i * 16 + q4 + rr;               // 0..WM-1
                        const float bias = aux1[m0 + half * WM + lrow];
#pragma unroll
                        for (int j = 0; j < FN; ++j)
                            lf[lrow * BNP + lcb + j * 16] = acc[i][j][rr] + bias;
                    }
            }
            __syncthreads();
            constexpr int CH = (WM * BN) / (256 * 4);
#pragma unroll
            for (int c = 0; c < CH; ++c) {
                const int e   = (c * 256 + tid) * 4;
                const int row = e / BN, col = e % BN;
                const f32x4 v = *(const f32x4*)&lf[row * BNP + col];
                *(f32x4*)(Cg + (size_t)(m0 + half * WM + row) * ldC + n0 + col) = v;
            }
            __syncthreads();
        }
    }
}

// ---------------------------------------------------------------------------
extern "C" void kernel_launch(void* const* d_in, const int* in_sizes, int n_in,
                              void* d_out, int out_size, void* d_ws, size_t ws_size,
                              hipStream_t stream) {
    const float* x  = (const float*)d_in[0];
    const float* W1 = (const float*)d_in[1];
    const float* b1 = (const float*)d_in[2];
    const float* Wl = (const float*)d_in[3];
    const float* bl = (const float*)d_in[4];
    const float* Wr = (const float*)d_in[5];
    const float* Wf = (const float*)d_in[6];
    const float* bf = (const float*)d_in[7];
    const float* W2 = (const float*)d_in[8];
    const float* b2 = (const float*)d_in[9];
    float* y = (float*)d_out;

    // workspace layout (u16 elements)
    u16* wsS   = (u16*)d_ws;
    u16* xT    = wsS;                       // [64][1024][256] = 16,777,216
    u16* h     = wsS + 16777216;            // [64][256][1024] = 16,777,216
    u16* r     = wsS + 33554432;            // [64][256][512]  =  8,388,608
    u16* W1T   = wsS + 41943040;            // [256][256]
    u16* W2T   = wsS + 42008576;            // [256][256]
    u16* WfT   = wsS + 42074112;            // [1024][512]
    u16* WsumT = wsS + 42598400;            // [3][512][1024]
    u16* WlTc  = wsS + 44171264;            // [3][512][3072]
    u16* muCat = wsS + 48889856;            // [3][64][3072]
    float* tmp8  = (float*)(wsS + 49479680);  // [8][3][64][512] f32
    float* blsum = tmp8 + 786432;             // [3][512] f32
    u16* outT = xT;                           // alias: xT dead after G1

    // prep: x-transpose + all weight prep in ONE launch, full-line writes
    prep_weights<<<dim3(5793), 256, 0, stream>>>(x, xT, W1, W2, Wf, Wl, Wr, bl,
                                                 W1T, W2T, WfT, WlTc, WsumT, blsum);

    // G1: h[b][n][s] = W1T[n][d] . xT[b][s][d] + b1[n], split fused mu -> muCat
    gemm2<128, 256, 256, 4, 0, 4, 3><<<dim3(512), 256, 0, stream>>>(
        W1T, xT, h, b1, nullptr, muCat, 262144, 262144, 256, 256, 1024);
    // beta partials: tmp8[ks][t][b][h] = muCat[t][b][kslice] . WlTc[t][h][kslice]
    gemm2<64, 64, 384, 1, 2, 1, 3><<<dim3(8, 8, 3), 256, 0, stream>>>(
        muCat, WlTc, tmp8, nullptr, nullptr, nullptr, 0, 0, 3072, 3072, 512);
    // G5: r[b*256+n][h] = relu( h-rows . WsumT[t(n)] + beta ), grouped rows
    gemm2<128, 128, 1024, 2, 1, 4, 3><<<dim3(512), 256, 0, stream>>>(
        h, WsumT, r, tmp8, blsum, nullptr, 0, 0, 1024, 1024, 512);
    // G6: outT[b][f][n] = WfT[f][:] . r[b][n][:] + bf[f]
    gemm2<256, 128, 512, 0, 0, 2, 3><<<dim3(512), 256, 0, stream>>>(
        WfT, r, outT, bf, nullptr, nullptr, 131072, 262144, 512, 512, 256);
    // G7: y[b][d][s] = W2T[d][:] . outT[b][s][:] + b2[d]
    gemm2<256, 128, 256, 3, 0, 8, 3><<<dim3(512), 256, 0, stream>>>(
        W2T, outT, y, b2, nullptr, nullptr, 262144, 262144, 256, 256, 1024);
}